// Round 10
// baseline (188.031 us; speedup 1.0000x reference)
//
#include <hip/hip_runtime.h>

#define DIM 128
#define UNROLL 8
#define ITER 2
#define BLOCK 1024
#define CHUNK (BLOCK * UNROLL)          // float4 units per iter = 8192
#define BCHUNK (CHUNK * ITER)           // float4 units per block = 16384

typedef float nfloat4 __attribute__((ext_vector_type(4)));  // native vector:
// __builtin_nontemporal_store requires a clang vector type, not HIP_vector_type.

// R9 (184 us) + amortized staging: each block processes ITER=2 chunks per one
// LDS staging of the 64 KB emb table, halving the 512 MiB of L2 staging reads
// and the per-block stage->barrier prologue count. 4096 one-shot blocks of
// 1024 threads (~16 blocks/CU lifetime, still fine-grained), 2 blocks/CU
// co-resident, 8 waves/SIMD.
//
// No vmcnt-drain hazard from the iter loop: ALL dist loads (ITER*UNROLL=16)
// issue up front, gathers come from LDS (lgkmcnt path), so no vmem consume
// ever follows a store -- the nt-store stream stays in flight continuously.
//
// Stores NONTEMPORAL (R4->R6 win): 1 GiB write stream bypasses L2, keeping
// the table + dist lines cache-resident.
__global__ __launch_bounds__(BLOCK, 8) void DistanceEmbedding_kernel(
    const float* __restrict__ dist,    // [R] distances
    const nfloat4* __restrict__ emb4,  // [DIM*DIM/4] table as float4
    const float* __restrict__ bins,    // [DIM] bin centers (monotone)
    nfloat4* __restrict__ out,         // [R*32] output
    unsigned total4)                   // R*32
{
    __shared__ float s_bins[DIM];
    __shared__ nfloat4 s_emb[DIM * DIM / 4];   // 64 KB

    #pragma unroll
    for (int i = 0; i < 4; ++i)
        s_emb[threadIdx.x + i * BLOCK] = emb4[threadIdx.x + i * BLOCK];
    if (threadIdx.x < DIM) s_bins[threadIdx.x] = bins[threadIdx.x];
    __syncthreads();

    // bins = linspace(0, 32, 128), spacing 32/127. Closed-form nearest bin
    // round(d*127/32) is within +/-1 of true argmin; refine against the real
    // bins with first-min tie-break (matches jnp.argmin). absmax==0 verified.
    const float inv_step = 127.0f / 32.0f;

    const unsigned base = blockIdx.x * (unsigned)BCHUNK + threadIdx.x;

    // All dist loads up front (broadcast within 32-lane groups, L1-hot).
    float d[ITER * UNROLL];
    #pragma unroll
    for (int k = 0; k < ITER * UNROLL; ++k) {
        const unsigned t = base + (unsigned)k * BLOCK;
        d[k] = dist[min(t, total4 - 1u) >> 5];
    }

    #pragma unroll
    for (int it = 0; it < ITER; ++it) {
        nfloat4 v[UNROLL];
        #pragma unroll
        for (int j = 0; j < UNROLL; ++j) {
            const int k = it * UNROLL + j;
            const unsigned t = base + (unsigned)k * BLOCK;
            const float dk = d[k];
            const float x = dk * inv_step;
            int i0 = (int)floorf(x + 0.5f);
            i0 = min(max(i0, 0), DIM - 1);
            const int lo = max(i0 - 1, 0);
            const int hi = min(i0 + 1, DIM - 1);
            int best = lo;
            float bd = fabsf(dk - s_bins[lo]);
            #pragma unroll
            for (int i = 0; i < 2; ++i) {
                const int cand = lo + 1 + i;
                if (cand <= hi) {
                    const float cd = fabsf(dk - s_bins[cand]);
                    if (cd < bd) { bd = cd; best = cand; }  // strict <: first-min
                }
            }
            v[j] = s_emb[best * (DIM / 4) + (int)(t & 31u)];
        }

        #pragma unroll
        for (int j = 0; j < UNROLL; ++j) {
            const int k = it * UNROLL + j;
            const unsigned t = base + (unsigned)k * BLOCK;
            if (t < total4) __builtin_nontemporal_store(v[j], &out[t]);
        }
    }
}

extern "C" void kernel_launch(void* const* d_in, const int* in_sizes, int n_in,
                              void* d_out, int out_size, void* d_ws, size_t ws_size,
                              hipStream_t stream) {
    const float* dist = (const float*)d_in[0];      // [2,1024,1024] f32
    const nfloat4* emb = (const nfloat4*)d_in[1];   // [128,128] f32
    const float* bins = (const float*)d_in[2];      // [128] f32
    nfloat4* out = (nfloat4*)d_out;                 // [2,1024,1024,128] f32

    const unsigned R = (unsigned)in_sizes[0];       // distance elements
    const unsigned total4 = R * (DIM / 4);          // float4 units in output

    const unsigned grid = (total4 + BCHUNK - 1) / BCHUNK;  // 4096 for bench shape
    DistanceEmbedding_kernel<<<grid, BLOCK, 0, stream>>>(
        dist, emb, bins, out, total4);
}

// Round 11
// 184.319 us; speedup vs baseline: 1.0201x; 1.0201x over previous
//
#include <hip/hip_runtime.h>

#define DIM 128
#define UNROLL 8
#define BLOCK 1024
#define CHUNK (BLOCK * UNROLL)   // float4 units per block = 8192

typedef float nfloat4 __attribute__((ext_vector_type(4)));  // native vector:
// __builtin_nontemporal_store requires a clang vector type, not HIP_vector_type.

// Best configuration (R9: 184 us, 5.83 TB/s effective vs 6.5 TB/s pure-fill).
// 8192 one-shot blocks of 1024 threads (~32 blocks/CU lifetime -> balanced),
// 2 blocks/CU co-resident (64.5 KB LDS each), 8 waves/SIMD.
//
// emb table staged in LDS once per block: the store-dependent gather is on
// the lgkm path (ds_read_b128), so the vmem queue carries ONLY broadcast
// dist loads + nt stores -- structurally fillBuffer plus a cheap load.
// (vmem-gather variant: 203 us; ITER=2 staging amortization: 188 us --
// staging is already hidden by the co-resident block.)
//
// Stores NONTEMPORAL: the 1 GiB write stream bypasses L2 so the table +
// dist lines stay cache-resident (cached-store variant: 213 us).
//
// Per-thread depth 8: UNROLL=16 at 4 waves/SIMD regressed (235 us) -- TLP
// beats per-wave MLP for this store-rate-limited kernel.
__global__ __launch_bounds__(BLOCK, 8) void DistanceEmbedding_kernel(
    const float* __restrict__ dist,    // [R] distances
    const nfloat4* __restrict__ emb4,  // [DIM*DIM/4] table as float4
    const float* __restrict__ bins,    // [DIM] bin centers (monotone)
    nfloat4* __restrict__ out,         // [R*32] output
    unsigned total4)                   // R*32
{
    __shared__ float s_bins[DIM];
    __shared__ nfloat4 s_emb[DIM * DIM / 4];   // 64 KB

    #pragma unroll
    for (int i = 0; i < 4; ++i)
        s_emb[threadIdx.x + i * BLOCK] = emb4[threadIdx.x + i * BLOCK];
    if (threadIdx.x < DIM) s_bins[threadIdx.x] = bins[threadIdx.x];
    __syncthreads();

    // bins = linspace(0, 32, 128), spacing 32/127. Closed-form nearest bin
    // round(d*127/32) is within +/-1 of true argmin; refine against the real
    // bins with first-min tie-break (matches jnp.argmin). absmax==0 verified.
    const float inv_step = 127.0f / 32.0f;

    const unsigned base = blockIdx.x * (unsigned)CHUNK + threadIdx.x;

    // All dist loads up front (broadcast within 32-lane groups, L1-hot).
    float d[UNROLL];
    #pragma unroll
    for (int k = 0; k < UNROLL; ++k) {
        const unsigned t = base + (unsigned)k * BLOCK;
        d[k] = dist[min(t, total4 - 1u) >> 5];
    }

    nfloat4 v[UNROLL];
    #pragma unroll
    for (int k = 0; k < UNROLL; ++k) {
        const unsigned t = base + (unsigned)k * BLOCK;
        const float dk = d[k];
        const float x = dk * inv_step;
        int i0 = (int)floorf(x + 0.5f);
        i0 = min(max(i0, 0), DIM - 1);
        const int lo = max(i0 - 1, 0);
        const int hi = min(i0 + 1, DIM - 1);
        int best = lo;
        float bd = fabsf(dk - s_bins[lo]);
        #pragma unroll
        for (int i = 0; i < 2; ++i) {
            const int cand = lo + 1 + i;
            if (cand <= hi) {
                const float cd = fabsf(dk - s_bins[cand]);
                if (cd < bd) { bd = cd; best = cand; }  // strict <: first-min
            }
        }
        v[k] = s_emb[best * (DIM / 4) + (int)(t & 31u)];
    }

    #pragma unroll
    for (int k = 0; k < UNROLL; ++k) {
        const unsigned t = base + (unsigned)k * BLOCK;
        if (t < total4) __builtin_nontemporal_store(v[k], &out[t]);
    }
}

extern "C" void kernel_launch(void* const* d_in, const int* in_sizes, int n_in,
                              void* d_out, int out_size, void* d_ws, size_t ws_size,
                              hipStream_t stream) {
    const float* dist = (const float*)d_in[0];      // [2,1024,1024] f32
    const nfloat4* emb = (const nfloat4*)d_in[1];   // [128,128] f32
    const float* bins = (const float*)d_in[2];      // [128] f32
    nfloat4* out = (nfloat4*)d_out;                 // [2,1024,1024,128] f32

    const unsigned R = (unsigned)in_sizes[0];       // distance elements
    const unsigned total4 = R * (DIM / 4);          // float4 units in output

    const unsigned grid = (total4 + CHUNK - 1) / CHUNK;   // 8192 for bench shape
    DistanceEmbedding_kernel<<<grid, BLOCK, 0, stream>>>(
        dist, emb, bins, out, total4);
}